// Round 6
// baseline (236.318 us; speedup 1.0000x reference)
//
#include <hip/hip_runtime.h>

#define NUM_NODES 200000
#define DIM 128
#define BATCH 1024
#define K_NEG 5
#define CAP 16
#define WCOL 96           /* j-columns per wave (3 MFMA column-groups) */
#define BCOL 384          /* j-columns per block (4 waves) */
#define THRESH 0.7f
#define FILL (-1.0e9f)

typedef __attribute__((ext_vector_type(8))) short short8;
typedef __attribute__((ext_vector_type(16))) float f32x16;

// round-to-nearest-even float -> bf16 bits (finite inputs only)
__device__ __forceinline__ unsigned short f2bf(float x) {
  unsigned u = __builtin_bit_cast(unsigned, x);
  return (unsigned short)((u + 0x7fffu + ((u >> 16) & 1u)) >> 16);
}

// ---------------- Threefry-2x32 (JAX-compatible) ----------------
__device__ __forceinline__ void tf2x32(unsigned k0, unsigned k1,
                                       unsigned x0, unsigned x1,
                                       unsigned* o0, unsigned* o1) {
  unsigned ks2 = k0 ^ k1 ^ 0x1BD11BDAu;
  unsigned v0 = x0 + k0, v1 = x1 + k1;
#define TFR(r) { v0 += v1; v1 = (v1 << r) | (v1 >> (32 - r)); v1 ^= v0; }
  TFR(13) TFR(15) TFR(26) TFR(6)   v0 += k1;  v1 += ks2 + 1u;
  TFR(17) TFR(29) TFR(16) TFR(24)  v0 += ks2; v1 += k0 + 2u;
  TFR(13) TFR(15) TFR(26) TFR(6)   v0 += k0;  v1 += k1 + 3u;
  TFR(17) TFR(29) TFR(16) TFR(24)  v0 += k1;  v1 += ks2 + 4u;
  TFR(13) TFR(15) TFR(26) TFR(6)   v0 += ks2; v1 += k0 + 5u;
#undef TFR
  *o0 = v0; *o1 = v1;
}

__device__ __forceinline__ unsigned rbits32(unsigned ka, unsigned kb, unsigned m) {
  unsigned o0, o1;
  tf2x32(ka, kb, 0u, m, &o0, &o1);
  return o0 ^ o1;
}

// ---- kernel 1: normalize src rows -> bf16 A-fragments (fragment-major), zero counters
// Fragment layout: chunk ((ms*8 + ks)*64 + lane64) is 8 bf16 (16 B) holding
// A[row = ms*32 + (lane64&31)][col = ks*16 + (lane64>>5)*8 + t], t=0..7.
__global__ void prep_kernel(const float* __restrict__ memory,
                            const int* __restrict__ src_nodes,
                            unsigned short* __restrict__ s16f,
                            int* __restrict__ cand_cnt) {
  int tid = threadIdx.x;
  int gid = blockIdx.x * 256 + tid;
  if (gid < BATCH) cand_cnt[gid] = 0;
  int row = blockIdx.x * 4 + (tid >> 6);   // 256 blocks x 4 waves = 1024 rows
  int L = tid & 63;                        // lane within the row's wave; cols 2L,2L+1
  int s = src_nodes[row];
  float2 v = ((const float2*)(memory + (size_t)s * DIM))[L];
  float ss = v.x * v.x + v.y * v.y;
#pragma unroll
  for (int off = 32; off > 0; off >>= 1) ss += __shfl_xor(ss, off);
  float inv = 1.0f / fmaxf(sqrtf(ss), 1e-12f);
  unsigned p = (unsigned)f2bf(v.x * inv) | ((unsigned)f2bf(v.y * inv) << 16);
  int ms = row >> 5, l32 = row & 31;
  int c = L >> 2;             // col chunk = col/8
  int ks = c >> 1, half = c & 1;
  ((unsigned*)s16f)[(((ms * 8 + ks) * 64) + half * 32 + l32) * 4 + (L & 3)] = p;
}

// ---- kernel 2: barrier-free MFMA sim scan, 96 j-columns per wave ----
// B fragments: RAW bf16 (scale-after-MFMA: acc > 0.7*|b_j|, value = acc/|b_j|),
// built in a single fused streaming pass (no fp32 staging array, no norm pass).
// 3 accumulator groups per wave -> 24 MFMAs per 8 A-fragment loads: the MFMA
// burst (~774 cyc) covers the L2 load latency; with 2 waves/SIMD the pipe
// saturates. Plain R1-style loop: no barriers, no sched pins, no dbuf.
__global__ __launch_bounds__(256, 2) void sim_scan_kernel(
    const float* __restrict__ memory,
    const unsigned short* __restrict__ s16f,
    const int* __restrict__ dst_nodes,
    int* __restrict__ cand_cnt,
    float* __restrict__ cand_val,
    int* __restrict__ cand_idx) {
  int tid = threadIdx.x;
  int wid = tid >> 6;
  int lane = tid & 63;
  int half = lane >> 5;
  int l32 = lane & 31;
  int jb = blockIdx.x * BCOL + wid * WCOL;   // wave's 96-column base

  // ---- build RAW bf16 B fragments (3 groups), sum-of-squares on the fly ----
  short8 bf0[8], bf1[8], bf2[8];
  float inv0, inv1, inv2, thr0, thr1, thr2;
#pragma unroll
  for (int js = 0; js < 3; ++js) {
    int j = jb + js * 32 + l32;
    int jc = j < NUM_NODES ? j : (NUM_NODES - 1);  // clamp; writes guarded later
    const float4* rp4 = (const float4*)(memory + (size_t)jc * DIM);
    float ss = 0.0f;
#pragma unroll
    for (int ks = 0; ks < 8; ++ks) {
      float4 a = rp4[ks * 4 + half * 2];
      float4 b = rp4[ks * 4 + half * 2 + 1];
      ss += a.x * a.x + a.y * a.y + a.z * a.z + a.w * a.w;
      ss += b.x * b.x + b.y * b.y + b.z * b.z + b.w * b.w;
      short8 f;
      f[0] = (short)f2bf(a.x); f[1] = (short)f2bf(a.y);
      f[2] = (short)f2bf(a.z); f[3] = (short)f2bf(a.w);
      f[4] = (short)f2bf(b.x); f[5] = (short)f2bf(b.y);
      f[6] = (short)f2bf(b.z); f[7] = (short)f2bf(b.w);
      if (js == 0) bf0[ks] = f; else if (js == 1) bf1[ks] = f; else bf2[ks] = f;
    }
    ss += __shfl_xor(ss, 32);            // combine the two half-rows
    float nrm = fmaxf(sqrtf(ss), 1e-12f);
    if (js == 0)      { inv0 = 1.0f / nrm; thr0 = THRESH * nrm; }
    else if (js == 1) { inv1 = 1.0f / nrm; thr1 = THRESH * nrm; }
    else              { inv2 = 1.0f / nrm; thr2 = THRESH * nrm; }
  }

  f32x16 Z;
#pragma unroll
  for (int i = 0; i < 16; ++i) Z[i] = 0.0f;

  const short8* __restrict__ af = (const short8*)s16f;

  // ---- main loop over 32 A-subtiles (whole batch), barrier-free ----
  for (int ms = 0; ms < 32; ++ms) {
    short8 a[8];
#pragma unroll
    for (int ks = 0; ks < 8; ++ks) a[ks] = af[(ms * 8 + ks) * 64 + lane];
    f32x16 acc0 = __builtin_amdgcn_mfma_f32_32x32x16_bf16(a[0], bf0[0], Z, 0, 0, 0);
    f32x16 acc1 = __builtin_amdgcn_mfma_f32_32x32x16_bf16(a[0], bf1[0], Z, 0, 0, 0);
    f32x16 acc2 = __builtin_amdgcn_mfma_f32_32x32x16_bf16(a[0], bf2[0], Z, 0, 0, 0);
#pragma unroll
    for (int ks = 1; ks < 8; ++ks) {
      acc0 = __builtin_amdgcn_mfma_f32_32x32x16_bf16(a[ks], bf0[ks], acc0, 0, 0, 0);
      acc1 = __builtin_amdgcn_mfma_f32_32x32x16_bf16(a[ks], bf1[ks], acc1, 0, 0, 0);
      acc2 = __builtin_amdgcn_mfma_f32_32x32x16_bf16(a[ks], bf2[ks], acc2, 0, 0, 0);
    }

    // cheap pre-check on RAW accumulators vs per-column raw thresholds
    float m0 = acc0[0], m1 = acc1[0], m2 = acc2[0];
#pragma unroll
    for (int i = 1; i < 16; ++i) {
      m0 = fmaxf(m0, acc0[i]); m1 = fmaxf(m1, acc1[i]); m2 = fmaxf(m2, acc2[i]);
    }
    if (m0 > thr0 || m1 > thr1 || m2 > thr2) {
      // C/D layout (m74/m101): col = lane&31, row = (reg&3) + 8*(reg>>2) + 4*(lane>>5)
#pragma unroll
      for (int js = 0; js < 3; ++js) {
        int gj = jb + js * 32 + l32;
        float thr = (js == 0) ? thr0 : (js == 1) ? thr1 : thr2;
        float inv = (js == 0) ? inv0 : (js == 1) ? inv1 : inv2;
#pragma unroll
        for (int r = 0; r < 16; ++r) {
          float raw = (js == 0) ? acc0[r] : (js == 1) ? acc1[r] : acc2[r];
          if (raw > thr) {
            int gi = ms * 32 + (r & 3) + 8 * (r >> 2) + 4 * half;
            if (gj < NUM_NODES && gj != dst_nodes[gi]) {
              int p = atomicAdd(&cand_cnt[gi], 1);
              if (p < CAP) {
                cand_val[gi * CAP + p] = raw * inv;
                cand_idx[gi * CAP + p] = gj;
              }
            }
          }
        }
      }
    }
  }
}

// ---- kernel 3: top-5 per row, threefry negatives, assemble ----
__global__ void finalize_kernel(const int* __restrict__ src_nodes,
                                const int* __restrict__ dst_nodes,
                                const float* __restrict__ labels,
                                const float* __restrict__ ts,
                                const int* __restrict__ cand_cnt,
                                const float* __restrict__ cand_val,
                                const int* __restrict__ cand_idx,
                                float* __restrict__ out) {
  int r = blockIdx.x * 256 + threadIdx.x;
  if (r >= BATCH) return;
  const int TOT = BATCH + BATCH * K_NEG;  // 6144
  int srcv = src_nodes[r];
  float tsv = ts[r];
  out[r] = (float)srcv;
  out[TOT + r] = (float)dst_nodes[r];
  float l = labels[r];
  out[2 * TOT + r] = l * 0.9f + (1.0f - l) * 0.1f;
  out[3 * TOT + r] = tsv;

  int cnt = cand_cnt[r];
  cnt = cnt < CAP ? cnt : CAP;
  float cv[CAP]; int ci[CAP];
  for (int i = 0; i < cnt; ++i) { cv[i] = cand_val[r * CAP + i]; ci[i] = cand_idx[r * CAP + i]; }

  // jax.random.split(key(42)) — partitionable/foldlike: k_i = threefry(key, 0, i)
  unsigned k1a, k1b, k2a, k2b;
  tf2x32(0u, 42u, 0u, 0u, &k1a, &k1b);
  tf2x32(0u, 42u, 0u, 1u, &k2a, &k2b);

  const unsigned span = 200000u;
  const unsigned mult = 167296u;  // 2^32 % span

  for (int s = 0; s < K_NEG; ++s) {
    int sel = -1;
    for (int i = 0; i < cnt; ++i)
      if (sel < 0 || cv[i] > cv[sel] || (cv[i] == cv[sel] && ci[i] < ci[sel])) sel = i;
    float v = FILL; int idx = 0;
    if (sel >= 0) { v = cv[sel]; idx = ci[sel]; cv[sel] = FILL; ci[sel] = 0x7fffffff; }
    bool is_real = v > (FILL + 1.0f);

    unsigned m = (unsigned)(r * K_NEG + s);
    unsigned hi = rbits32(k1a, k1b, m);
    unsigned lo = rbits32(k2a, k2b, m);
    unsigned off = ((hi % span) * mult + (lo % span)) % span;  // uint32 wrap, as JAX
    int rd = (int)off;
    if (rd == srcv) rd = (rd + 1) % NUM_NODES;
    int fd = is_real ? idx : rd;

    int mi = (int)m;
    out[BATCH + mi] = (float)srcv;
    out[TOT + BATCH + mi] = (float)fd;
    out[2 * TOT + BATCH + mi] = 0.1f;   // smoothing of label 0
    out[3 * TOT + BATCH + mi] = tsv;
    out[4 * TOT + mi] = v;
  }
}

extern "C" void kernel_launch(void* const* d_in, const int* in_sizes, int n_in,
                              void* d_out, int out_size, void* d_ws, size_t ws_size,
                              hipStream_t stream) {
  const int* src = (const int*)d_in[0];
  const int* dst = (const int*)d_in[1];
  const float* labels = (const float*)d_in[2];
  const float* ts = (const float*)d_in[3];
  const float* memory = (const float*)d_in[4];
  float* out = (float*)d_out;

  char* ws = (char*)d_ws;
  unsigned short* s16f = (unsigned short*)ws;       // 1024*128*2 = 262144 B (fragment-major)
  int* cand_cnt = (int*)(ws + 262144);              // 4096 B
  float* cand_val = (float*)(ws + 266240);          // 65536 B
  int* cand_idx = (int*)(ws + 331776);              // 65536 B

  prep_kernel<<<256, 256, 0, stream>>>(memory, src, s16f, cand_cnt);
  int jblocks = (NUM_NODES + BCOL - 1) / BCOL;      // 521
  sim_scan_kernel<<<jblocks, 256, 0, stream>>>(memory, s16f, dst, cand_cnt, cand_val, cand_idx);
  finalize_kernel<<<(BATCH + 255) / 256, 256, 0, stream>>>(src, dst, labels, ts,
                                                           cand_cnt, cand_val, cand_idx, out);
}

// Round 7
// 222.270 us; speedup vs baseline: 1.0632x; 1.0632x over previous
//
#include <hip/hip_runtime.h>

#define NUM_NODES 200000
#define DIM 128
#define BATCH 1024
#define K_NEG 5
#define CAP 16
#define NBLK 250          /* sim blocks; 200000 = 250 * 800 */
#define CPB 800           /* columns per block */
#define TCOL 32           /* columns per staged tile; 800 = 25 * 32 */
#define THRESH 0.7f
#define FILL (-1.0e9f)

typedef __attribute__((ext_vector_type(8))) short short8;
typedef __attribute__((ext_vector_type(16))) float f32x16;

// round-to-nearest-even float -> bf16 bits (finite inputs only)
__device__ __forceinline__ unsigned short f2bf(float x) {
  unsigned u = __builtin_bit_cast(unsigned, x);
  return (unsigned short)((u + 0x7fffu + ((u >> 16) & 1u)) >> 16);
}

// async global->LDS: 16 bytes per lane; LDS dest = wave-uniform base + lane*16
__device__ __forceinline__ void stage16(const void* g, void* l) {
  __builtin_amdgcn_global_load_lds(
      (const __attribute__((address_space(1))) unsigned int*)g,
      (__attribute__((address_space(3))) unsigned int*)l,
      16, 0, 0);
}

// ---------------- Threefry-2x32 (JAX-compatible) ----------------
__device__ __forceinline__ void tf2x32(unsigned k0, unsigned k1,
                                       unsigned x0, unsigned x1,
                                       unsigned* o0, unsigned* o1) {
  unsigned ks2 = k0 ^ k1 ^ 0x1BD11BDAu;
  unsigned v0 = x0 + k0, v1 = x1 + k1;
#define TFR(r) { v0 += v1; v1 = (v1 << r) | (v1 >> (32 - r)); v1 ^= v0; }
  TFR(13) TFR(15) TFR(26) TFR(6)   v0 += k1;  v1 += ks2 + 1u;
  TFR(17) TFR(29) TFR(16) TFR(24)  v0 += ks2; v1 += k0 + 2u;
  TFR(13) TFR(15) TFR(26) TFR(6)   v0 += k0;  v1 += k1 + 3u;
  TFR(17) TFR(29) TFR(16) TFR(24)  v0 += k1;  v1 += ks2 + 4u;
  TFR(13) TFR(15) TFR(26) TFR(6)   v0 += ks2; v1 += k0 + 5u;
#undef TFR
  *o0 = v0; *o1 = v1;
}

__device__ __forceinline__ unsigned rbits32(unsigned ka, unsigned kb, unsigned m) {
  unsigned o0, o1;
  tf2x32(ka, kb, 0u, m, &o0, &o1);
  return o0 ^ o1;
}

// ---- kernel 1: normalize src rows -> bf16 A-fragments (fragment-major), zero counters
// Fragment layout: chunk ((ms*8 + ks)*64 + lane64) is 8 bf16 (16 B) holding
// A[row = ms*32 + (lane64&31)][col = ks*16 + (lane64>>5)*8 + t], t=0..7.
__global__ void prep_kernel(const float* __restrict__ memory,
                            const int* __restrict__ src_nodes,
                            unsigned short* __restrict__ s16f,
                            int* __restrict__ cand_cnt) {
  int tid = threadIdx.x;
  int gid = blockIdx.x * 256 + tid;
  if (gid < BATCH) cand_cnt[gid] = 0;
  int row = blockIdx.x * 4 + (tid >> 6);   // 256 blocks x 4 waves = 1024 rows
  int L = tid & 63;                        // lane within the row's wave; cols 2L,2L+1
  int s = src_nodes[row];
  float2 v = ((const float2*)(memory + (size_t)s * DIM))[L];
  float ss = v.x * v.x + v.y * v.y;
#pragma unroll
  for (int off = 32; off > 0; off >>= 1) ss += __shfl_xor(ss, off);
  float inv = 1.0f / fmaxf(sqrtf(ss), 1e-12f);
  unsigned p = (unsigned)f2bf(v.x * inv) | ((unsigned)f2bf(v.y * inv) << 16);
  int ms = row >> 5, l32 = row & 31;
  int c = L >> 2;             // col chunk = col/8
  int ks = c >> 1, half = c & 1;
  ((unsigned*)s16f)[(((ms * 8 + ks) * 64) + half * 32 + l32) * 4 + (L & 3)] = p;
}

// ---- kernel 2: read-once MFMA sim scan ----
// Dataflow inversion: A (1024 src rows, bf16 fragments) lives in REGISTERS
// (4 subtiles/wave x 8 waves = all 32), read from L2 exactly once. B (node
// memory) is streamed from HBM exactly once: 16 KB tiles (32 cols) staged
// via global_load_lds into a double buffer, with the per-lane GLOBAL address
// permuted so LDS holds [kchunk][col] order -> conflict-free ds_read_b128
// fragment reads. One barrier per tile; staged loads get the whole MFMA
// phase (~2000 cyc) to land, hiding HBM latency. B normalization is fused
// scale-after-MFMA (acc > 0.7*|b_j|; value = acc/|b_j|).
__global__ __launch_bounds__(512, 2) void sim_scan_kernel(
    const float* __restrict__ memory,
    const unsigned short* __restrict__ s16f,
    const int* __restrict__ dst_nodes,
    int* __restrict__ cand_cnt,
    float* __restrict__ cand_val,
    int* __restrict__ cand_idx) {
  __shared__ char bbuf[2][16384];   // 2 x (32 cols x 512 B) B-tile double buffer

  int tid = threadIdx.x;
  int wid = tid >> 6;
  int lane = tid & 63;
  int half = lane >> 5;
  int l32 = lane & 31;
  int jb0 = blockIdx.x * CPB;       // block's column range [jb0, jb0+800)

  // ---- stage B-tile 0; per-lane global addr permuted to [kchunk][col] ----
  // chunk i (0..1023): col = i&31, kc = i>>5; LDS offset = i*16 (linear).
  {
    const char* mb = (const char*)memory;
    int i1 = tid;
    stage16(mb + (size_t)(jb0 + (i1 & 31)) * 512 + ((i1 >> 5) << 4),
            (char*)&bbuf[0][0] + (wid << 10));
    int i2 = tid + 512;
    stage16(mb + (size_t)(jb0 + (i2 & 31)) * 512 + ((i2 >> 5) << 4),
            (char*)&bbuf[0][0] + 8192 + (wid << 10));
  }

  // ---- load this wave's 4 A-subtiles into registers (once) ----
  const short8* __restrict__ af = (const short8*)s16f;
  short8 a[4][8];
#pragma unroll
  for (int m = 0; m < 4; ++m)
#pragma unroll
    for (int ks = 0; ks < 8; ++ks)
      a[m][ks] = af[(((wid * 4 + m) * 8) + ks) * 64 + lane];

  f32x16 Z;
#pragma unroll
  for (int i = 0; i < 16; ++i) Z[i] = 0.0f;

  __syncthreads();   // drains vmcnt(0): tile 0 staged
  int cur = 0;

  // ---- main loop over 25 B-tiles ----
  for (int t = 0; t < 25; ++t) {
    if (t < 24) {
      const char* mb = (const char*)memory;
      int jn = jb0 + (t + 1) * TCOL;
      int i1 = tid;
      stage16(mb + (size_t)(jn + (i1 & 31)) * 512 + ((i1 >> 5) << 4),
              (char*)&bbuf[cur ^ 1][0] + (wid << 10));
      int i2 = tid + 512;
      stage16(mb + (size_t)(jn + (i2 & 31)) * 512 + ((i2 >> 5) << 4),
              (char*)&bbuf[cur ^ 1][0] + 8192 + (wid << 10));
    }

    // ---- build RAW bf16 B fragments from LDS (conflict-free) ----
    // lane (l32,half) needs cols ks*16+half*8+0..7 of col j=jb+l32:
    // chunks kc = ks*4 + half*2, +1 at LDS (kc*32 + l32)*16.
    const float4* lbp = (const float4*)(&bbuf[cur][0] + (half << 10) + (l32 << 4));
    short8 bf[8];
    float ss = 0.0f;
#pragma unroll
    for (int ks = 0; ks < 8; ++ks) {
      float4 q0 = lbp[ks * 128];        // kc = ks*4 + half*2
      float4 q1 = lbp[ks * 128 + 32];   // kc + 1
      ss += q0.x * q0.x + q0.y * q0.y + q0.z * q0.z + q0.w * q0.w;
      ss += q1.x * q1.x + q1.y * q1.y + q1.z * q1.z + q1.w * q1.w;
      short8 f;
      f[0] = (short)f2bf(q0.x); f[1] = (short)f2bf(q0.y);
      f[2] = (short)f2bf(q0.z); f[3] = (short)f2bf(q0.w);
      f[4] = (short)f2bf(q1.x); f[5] = (short)f2bf(q1.y);
      f[6] = (short)f2bf(q1.z); f[7] = (short)f2bf(q1.w);
      bf[ks] = f;
    }
    ss += __shfl_xor(ss, 32);           // combine the two half-rows
    float nrm = fmaxf(sqrtf(ss), 1e-12f);
    float inv = 1.0f / nrm;
    float thr = THRESH * nrm;
    int gj = jb0 + t * TCOL + l32;      // this lane's column (always < NUM_NODES)

    // ---- 32 MFMAs: 4 A-subtiles x 8 ks, two interleaved acc chains ----
#pragma unroll
    for (int mp = 0; mp < 2; ++mp) {
      f32x16 accA = __builtin_amdgcn_mfma_f32_32x32x16_bf16(a[mp * 2][0], bf[0], Z, 0, 0, 0);
      f32x16 accB = __builtin_amdgcn_mfma_f32_32x32x16_bf16(a[mp * 2 + 1][0], bf[0], Z, 0, 0, 0);
#pragma unroll
      for (int ks = 1; ks < 8; ++ks) {
        accA = __builtin_amdgcn_mfma_f32_32x32x16_bf16(a[mp * 2][ks], bf[ks], accA, 0, 0, 0);
        accB = __builtin_amdgcn_mfma_f32_32x32x16_bf16(a[mp * 2 + 1][ks], bf[ks], accB, 0, 0, 0);
      }
      float mA = accA[0], mB = accB[0];
#pragma unroll
      for (int i = 1; i < 16; ++i) { mA = fmaxf(mA, accA[i]); mB = fmaxf(mB, accB[i]); }
      if (mA > thr || mB > thr) {
        // C/D layout (m74/m101): col=lane&31, row=(r&3)+8*(r>>2)+4*(lane>>5)
#pragma unroll
        for (int e = 0; e < 2; ++e) {
          int ms = wid * 4 + mp * 2 + e;
#pragma unroll
          for (int r = 0; r < 16; ++r) {
            float raw = (e == 0) ? accA[r] : accB[r];
            if (raw > thr) {
              int gi = ms * 32 + (r & 3) + 8 * (r >> 2) + 4 * half;
              if (gj != dst_nodes[gi]) {
                int p = atomicAdd(&cand_cnt[gi], 1);
                if (p < CAP) {
                  cand_val[gi * CAP + p] = raw * inv;
                  cand_idx[gi * CAP + p] = gj;
                }
              }
            }
          }
        }
      }
    }

    __syncthreads();   // drains vmcnt: next tile staged; all waves done with cur
    cur ^= 1;
  }
}

// ---- kernel 3: top-5 per row, threefry negatives, assemble ----
__global__ void finalize_kernel(const int* __restrict__ src_nodes,
                                const int* __restrict__ dst_nodes,
                                const float* __restrict__ labels,
                                const float* __restrict__ ts,
                                const int* __restrict__ cand_cnt,
                                const float* __restrict__ cand_val,
                                const int* __restrict__ cand_idx,
                                float* __restrict__ out) {
  int r = blockIdx.x * 256 + threadIdx.x;
  if (r >= BATCH) return;
  const int TOT = BATCH + BATCH * K_NEG;  // 6144
  int srcv = src_nodes[r];
  float tsv = ts[r];
  out[r] = (float)srcv;
  out[TOT + r] = (float)dst_nodes[r];
  float l = labels[r];
  out[2 * TOT + r] = l * 0.9f + (1.0f - l) * 0.1f;
  out[3 * TOT + r] = tsv;

  int cnt = cand_cnt[r];
  cnt = cnt < CAP ? cnt : CAP;
  float cv[CAP]; int ci[CAP];
  for (int i = 0; i < cnt; ++i) { cv[i] = cand_val[r * CAP + i]; ci[i] = cand_idx[r * CAP + i]; }

  // jax.random.split(key(42)) — partitionable/foldlike: k_i = threefry(key, 0, i)
  unsigned k1a, k1b, k2a, k2b;
  tf2x32(0u, 42u, 0u, 0u, &k1a, &k1b);
  tf2x32(0u, 42u, 0u, 1u, &k2a, &k2b);

  const unsigned span = 200000u;
  const unsigned mult = 167296u;  // 2^32 % span

  for (int s = 0; s < K_NEG; ++s) {
    int sel = -1;
    for (int i = 0; i < cnt; ++i)
      if (sel < 0 || cv[i] > cv[sel] || (cv[i] == cv[sel] && ci[i] < ci[sel])) sel = i;
    float v = FILL; int idx = 0;
    if (sel >= 0) { v = cv[sel]; idx = ci[sel]; cv[sel] = FILL; ci[sel] = 0x7fffffff; }
    bool is_real = v > (FILL + 1.0f);

    unsigned m = (unsigned)(r * K_NEG + s);
    unsigned hi = rbits32(k1a, k1b, m);
    unsigned lo = rbits32(k2a, k2b, m);
    unsigned off = ((hi % span) * mult + (lo % span)) % span;  // uint32 wrap, as JAX
    int rd = (int)off;
    if (rd == srcv) rd = (rd + 1) % NUM_NODES;
    int fd = is_real ? idx : rd;

    int mi = (int)m;
    out[BATCH + mi] = (float)srcv;
    out[TOT + BATCH + mi] = (float)fd;
    out[2 * TOT + BATCH + mi] = 0.1f;   // smoothing of label 0
    out[3 * TOT + BATCH + mi] = tsv;
    out[4 * TOT + mi] = v;
  }
}

extern "C" void kernel_launch(void* const* d_in, const int* in_sizes, int n_in,
                              void* d_out, int out_size, void* d_ws, size_t ws_size,
                              hipStream_t stream) {
  const int* src = (const int*)d_in[0];
  const int* dst = (const int*)d_in[1];
  const float* labels = (const float*)d_in[2];
  const float* ts = (const float*)d_in[3];
  const float* memory = (const float*)d_in[4];
  float* out = (float*)d_out;

  char* ws = (char*)d_ws;
  unsigned short* s16f = (unsigned short*)ws;       // 1024*128*2 = 262144 B (fragment-major)
  int* cand_cnt = (int*)(ws + 262144);              // 4096 B
  float* cand_val = (float*)(ws + 266240);          // 65536 B
  int* cand_idx = (int*)(ws + 331776);              // 65536 B

  prep_kernel<<<256, 256, 0, stream>>>(memory, src, s16f, cand_cnt);
  sim_scan_kernel<<<NBLK, 512, 0, stream>>>(memory, s16f, dst, cand_cnt, cand_val, cand_idx);
  finalize_kernel<<<(BATCH + 255) / 256, 256, 0, stream>>>(src, dst, labels, ts,
                                                           cand_cnt, cand_val, cand_idx, out);
}

// Round 9
// 188.508 us; speedup vs baseline: 1.2536x; 1.1791x over previous
//
#include <hip/hip_runtime.h>

#define NUM_NODES 200000
#define DIM 128
#define BATCH 1024
#define K_NEG 5
#define CAP 16
#define NBLK 250          /* sim blocks; 200000 = 250 * 800 */
#define CPB 800           /* columns per block */
#define TCOL 32           /* columns per tile; 800 = 25 * 32 */
#define NT 25             /* tiles per block */
#define THRESH 0.7f
#define FILL (-1.0e9f)

typedef __attribute__((ext_vector_type(8))) short short8;
typedef __attribute__((ext_vector_type(16))) float f32x16;

// round-to-nearest-even float -> bf16 bits (finite inputs only)
__device__ __forceinline__ unsigned short f2bf(float x) {
  unsigned u = __builtin_bit_cast(unsigned, x);
  return (unsigned short)((u + 0x7fffu + ((u >> 16) & 1u)) >> 16);
}

// async global->LDS: 16 bytes per lane; LDS dest = wave-uniform base + lane*16
__device__ __forceinline__ void stage16(const void* g, void* l) {
  __builtin_amdgcn_global_load_lds(
      (const __attribute__((address_space(1))) unsigned int*)g,
      (__attribute__((address_space(3))) unsigned int*)l,
      16, 0, 0);
}

// ---------------- Threefry-2x32 (JAX-compatible) ----------------
__device__ __forceinline__ void tf2x32(unsigned k0, unsigned k1,
                                       unsigned x0, unsigned x1,
                                       unsigned* o0, unsigned* o1) {
  unsigned ks2 = k0 ^ k1 ^ 0x1BD11BDAu;
  unsigned v0 = x0 + k0, v1 = x1 + k1;
#define TFR(r) { v0 += v1; v1 = (v1 << r) | (v1 >> (32 - r)); v1 ^= v0; }
  TFR(13) TFR(15) TFR(26) TFR(6)   v0 += k1;  v1 += ks2 + 1u;
  TFR(17) TFR(29) TFR(16) TFR(24)  v0 += ks2; v1 += k0 + 2u;
  TFR(13) TFR(15) TFR(26) TFR(6)   v0 += k0;  v1 += k1 + 3u;
  TFR(17) TFR(29) TFR(16) TFR(24)  v0 += k1;  v1 += ks2 + 4u;
  TFR(13) TFR(15) TFR(26) TFR(6)   v0 += ks2; v1 += k0 + 5u;
#undef TFR
  *o0 = v0; *o1 = v1;
}

__device__ __forceinline__ unsigned rbits32(unsigned ka, unsigned kb, unsigned m) {
  unsigned o0, o1;
  tf2x32(ka, kb, 0u, m, &o0, &o1);
  return o0 ^ o1;
}

// ---- kernel 1: normalize src rows -> bf16 A-fragments (fragment-major), zero counters
// Fragment layout: chunk ((ms*8 + ks)*64 + lane64) is 8 bf16 (16 B) holding
// A[row = ms*32 + (lane64&31)][col = ks*16 + (lane64>>5)*8 + t], t=0..7.
__global__ void prep_kernel(const float* __restrict__ memory,
                            const int* __restrict__ src_nodes,
                            unsigned short* __restrict__ s16f,
                            int* __restrict__ cand_cnt) {
  int tid = threadIdx.x;
  int gid = blockIdx.x * 256 + tid;
  if (gid < BATCH) cand_cnt[gid] = 0;
  int row = blockIdx.x * 4 + (tid >> 6);   // 256 blocks x 4 waves = 1024 rows
  int L = tid & 63;                        // lane within the row's wave; cols 2L,2L+1
  int s = src_nodes[row];
  float2 v = ((const float2*)(memory + (size_t)s * DIM))[L];
  float ss = v.x * v.x + v.y * v.y;
#pragma unroll
  for (int off = 32; off > 0; off >>= 1) ss += __shfl_xor(ss, off);
  float inv = 1.0f / fmaxf(sqrtf(ss), 1e-12f);
  unsigned p = (unsigned)f2bf(v.x * inv) | ((unsigned)f2bf(v.y * inv) << 16);
  int ms = row >> 5, l32 = row & 31;
  int c = L >> 2;             // col chunk = col/8
  int ks = c >> 1, half = c & 1;
  ((unsigned*)s16f)[(((ms * 8 + ks) * 64) + half * 32 + l32) * 4 + (L & 3)] = p;
}

// ---- kernel 2: read-once MFMA sim scan, convert-once-per-block ----
// A: each of 8 waves holds 4 subtiles in registers (128 VGPR), loaded once.
// B: 32-col raw fp32 tiles staged HBM->LDS once (global_load_lds, [seg16][col]
// order); conversion to bf16 fragments + column norms done ONCE per block
// (each wave converts its own 4 columns) into a double-buffered frag LDS
// buffer; all waves then ds_read_b128 fragments (consecutive-16B pattern) and
// run 32 MFMAs each. Scale-after-MFMA: acc > 0.7*|b_j|, value = acc/|b_j|.
// HBM-bound regime: 102 MB read exactly once (~16 us floor).
__global__ __launch_bounds__(512, 2) void sim_scan_kernel(
    const float* __restrict__ memory,
    const unsigned short* __restrict__ s16f,
    const int* __restrict__ dst_nodes,
    int* __restrict__ cand_cnt,
    float* __restrict__ cand_val,
    int* __restrict__ cand_idx) {
  __shared__ char rawb[16384];               // raw fp32 tile, [seg16 0..31][col 0..31] x 16 B
  __shared__ unsigned short fragb[2][4096];  // bf16 frags, [seg 0..15][col 0..31] x 16 B
  __shared__ float nrmb[2][32];              // per-column L2 norms

  int tid = threadIdx.x;
  int wid = tid >> 6;
  int lane = tid & 63;
  int half = lane >> 5;
  int l32 = lane & 31;
  int jb0 = blockIdx.x * CPB;

  const char* mb = (const char*)memory;

  // stage tile t: unit u (0..1023) at LDS u*16 <- global (jb+ (u&31))*512 + (u>>5)*16
#define STAGE(t) {                                                              \
    int jn = jb0 + (t) * TCOL;                                                  \
    stage16(mb + (size_t)(jn + (tid & 31)) * 512 + ((tid >> 5) << 4),           \
            (char*)rawb + (wid << 10));                                         \
    stage16(mb + (size_t)(jn + (tid & 31)) * 512 + (((tid >> 5) + 16) << 4),    \
            (char*)rawb + 8192 + (wid << 10));                                  \
  }

  // convert own 4 columns of staged tile into frag[p]/nrm[p]
  int ccol = wid * 4 + (lane & 3);   // col 0..31 (per wave: 4 cols)
  int cseg = lane >> 2;              // seg 0..15 (elements [seg*8, seg*8+8))
#define CONVERT(p) {                                                            \
    float4 q0 = *(const float4*)(rawb + (((2 * cseg) * 32 + ccol) << 4));       \
    float4 q1 = *(const float4*)(rawb + (((2 * cseg + 1) * 32 + ccol) << 4));   \
    float ss = q0.x * q0.x + q0.y * q0.y + q0.z * q0.z + q0.w * q0.w            \
             + q1.x * q1.x + q1.y * q1.y + q1.z * q1.z + q1.w * q1.w;           \
    ss += __shfl_xor(ss, 4); ss += __shfl_xor(ss, 8);                           \
    ss += __shfl_xor(ss, 16); ss += __shfl_xor(ss, 32);                         \
    short8 f;                                                                   \
    f[0] = (short)f2bf(q0.x); f[1] = (short)f2bf(q0.y);                         \
    f[2] = (short)f2bf(q0.z); f[3] = (short)f2bf(q0.w);                         \
    f[4] = (short)f2bf(q1.x); f[5] = (short)f2bf(q1.y);                         \
    f[6] = (short)f2bf(q1.z); f[7] = (short)f2bf(q1.w);                         \
    *(short8*)((char*)fragb[p] + ((cseg * 32 + ccol) << 4)) = f;                \
    if (cseg == 0) nrmb[p][ccol] = fmaxf(sqrtf(ss), 1e-12f);                    \
  }

  // ---- prologue ----
  STAGE(0);
  const short8* __restrict__ af = (const short8*)s16f;
  short8 a[4][8];
#pragma unroll
  for (int m = 0; m < 4; ++m)
#pragma unroll
    for (int ks = 0; ks < 8; ++ks)
      a[m][ks] = af[(((wid * 4 + m) * 8) + ks) * 64 + lane];
  __syncthreads();          // tile0 raw ready
  CONVERT(0);
  __syncthreads();          // frag[0] visible, raw free
  STAGE(1);
  __syncthreads();          // tile1 raw ready (one exposed drain, prologue only)

  f32x16 Z;
#pragma unroll
  for (int i = 0; i < 16; ++i) Z[i] = 0.0f;

  // ---- main loop ----
  for (int t = 0; t < NT; ++t) {
    if (t < NT - 1) CONVERT((t + 1) & 1);    // reads raw (tile t+1)
    __syncthreads();                          // frag[(t+1)&1] visible; raw free
    if (t < NT - 2) STAGE(t + 2);             // restage raw; drains at loop-end barrier

    // ---- MFMA phase on frag[t&1] ----
    int p = t & 1;
    float nv = nrmb[p][l32];
    float thr = THRESH * nv;
    float invv = 1.0f / nv;
    int gj = jb0 + t * TCOL + l32;
    short8 bf[8];
#pragma unroll
    for (int ks = 0; ks < 8; ++ks)
      bf[ks] = *(const short8*)((char*)fragb[p] + (((2 * ks + half) * 32 + l32) << 4));

#pragma unroll
    for (int mp = 0; mp < 2; ++mp) {
      f32x16 accA = __builtin_amdgcn_mfma_f32_32x32x16_bf16(a[mp * 2][0], bf[0], Z, 0, 0, 0);
      f32x16 accB = __builtin_amdgcn_mfma_f32_32x32x16_bf16(a[mp * 2 + 1][0], bf[0], Z, 0, 0, 0);
#pragma unroll
      for (int ks = 1; ks < 8; ++ks) {
        accA = __builtin_amdgcn_mfma_f32_32x32x16_bf16(a[mp * 2][ks], bf[ks], accA, 0, 0, 0);
        accB = __builtin_amdgcn_mfma_f32_32x32x16_bf16(a[mp * 2 + 1][ks], bf[ks], accB, 0, 0, 0);
      }
      float mA = accA[0], mB = accB[0];
#pragma unroll
      for (int i = 1; i < 16; ++i) { mA = fmaxf(mA, accA[i]); mB = fmaxf(mB, accB[i]); }
      if (mA > thr || mB > thr) {
        // C/D layout (m74/m101): col=lane&31, row=(r&3)+8*(r>>2)+4*(lane>>5)
#pragma unroll
        for (int e = 0; e < 2; ++e) {
#pragma unroll
          for (int r = 0; r < 16; ++r) {
            float raw = (e == 0) ? accA[r] : accB[r];
            if (raw > thr) {
              int gi = (wid * 4 + mp * 2 + e) * 32 + (r & 3) + 8 * (r >> 2) + 4 * half;
              if (gj != dst_nodes[gi]) {
                int pq = atomicAdd(&cand_cnt[gi], 1);
                if (pq < CAP) {
                  cand_val[gi * CAP + pq] = raw * invv;
                  cand_idx[gi * CAP + pq] = gj;
                }
              }
            }
          }
        }
      }
    }

    __syncthreads();   // drains stage(t+2); frag[t&1] free for next convert
  }
#undef STAGE
#undef CONVERT
}

// ---- kernel 3: top-5 per row, threefry negatives, assemble ----
__global__ void finalize_kernel(const int* __restrict__ src_nodes,
                                const int* __restrict__ dst_nodes,
                                const float* __restrict__ labels,
                                const float* __restrict__ ts,
                                const int* __restrict__ cand_cnt,
                                const float* __restrict__ cand_val,
                                const int* __restrict__ cand_idx,
                                float* __restrict__ out) {
  int r = blockIdx.x * 256 + threadIdx.x;
  if (r >= BATCH) return;
  const int TOT = BATCH + BATCH * K_NEG;  // 6144
  int srcv = src_nodes[r];
  float tsv = ts[r];
  out[r] = (float)srcv;
  out[TOT + r] = (float)dst_nodes[r];
  float l = labels[r];
  out[2 * TOT + r] = l * 0.9f + (1.0f - l) * 0.1f;
  out[3 * TOT + r] = tsv;

  int cnt = cand_cnt[r];
  cnt = cnt < CAP ? cnt : CAP;
  float cv[CAP]; int ci[CAP];
  for (int i = 0; i < cnt; ++i) { cv[i] = cand_val[r * CAP + i]; ci[i] = cand_idx[r * CAP + i]; }

  // jax.random.split(key(42)) — partitionable/foldlike: k_i = threefry(key, 0, i)
  unsigned k1a, k1b, k2a, k2b;
  tf2x32(0u, 42u, 0u, 0u, &k1a, &k1b);
  tf2x32(0u, 42u, 0u, 1u, &k2a, &k2b);

  const unsigned span = 200000u;
  const unsigned mult = 167296u;  // 2^32 % span

  for (int s = 0; s < K_NEG; ++s) {
    int sel = -1;
    for (int i = 0; i < cnt; ++i)
      if (sel < 0 || cv[i] > cv[sel] || (cv[i] == cv[sel] && ci[i] < ci[sel])) sel = i;
    float v = FILL; int idx = 0;
    if (sel >= 0) { v = cv[sel]; idx = ci[sel]; cv[sel] = FILL; ci[sel] = 0x7fffffff; }
    bool is_real = v > (FILL + 1.0f);

    unsigned m = (unsigned)(r * K_NEG + s);
    unsigned hi = rbits32(k1a, k1b, m);
    unsigned lo = rbits32(k2a, k2b, m);
    unsigned off = ((hi % span) * mult + (lo % span)) % span;  // uint32 wrap, as JAX
    int rd = (int)off;
    if (rd == srcv) rd = (rd + 1) % NUM_NODES;
    int fd = is_real ? idx : rd;

    int mi = (int)m;
    out[BATCH + mi] = (float)srcv;
    out[TOT + BATCH + mi] = (float)fd;
    out[2 * TOT + BATCH + mi] = 0.1f;   // smoothing of label 0
    out[3 * TOT + BATCH + mi] = tsv;
    out[4 * TOT + mi] = v;
  }
}

extern "C" void kernel_launch(void* const* d_in, const int* in_sizes, int n_in,
                              void* d_out, int out_size, void* d_ws, size_t ws_size,
                              hipStream_t stream) {
  const int* src = (const int*)d_in[0];
  const int* dst = (const int*)d_in[1];
  const float* labels = (const float*)d_in[2];
  const float* ts = (const float*)d_in[3];
  const float* memory = (const float*)d_in[4];
  float* out = (float*)d_out;

  char* ws = (char*)d_ws;
  unsigned short* s16f = (unsigned short*)ws;       // 1024*128*2 = 262144 B (fragment-major)
  int* cand_cnt = (int*)(ws + 262144);              // 4096 B
  float* cand_val = (float*)(ws + 266240);          // 65536 B
  int* cand_idx = (int*)(ws + 331776);              // 65536 B

  prep_kernel<<<256, 256, 0, stream>>>(memory, src, s16f, cand_cnt);
  sim_scan_kernel<<<NBLK, 512, 0, stream>>>(memory, s16f, dst, cand_cnt, cand_val, cand_idx);
  finalize_kernel<<<(BATCH + 255) / 256, 256, 0, stream>>>(src, dst, labels, ts,
                                                           cand_cnt, cand_val, cand_idx, out);
}